// Round 1
// baseline (1733.988 us; speedup 1.0000x reference)
//
#include <hip/hip_runtime.h>

#define N_NODES 100000
#define E_EDGES 1600000

// ---------------------------------------------------------------------------
// GEMM: H[N,DOUT] = act(X)[N,64] @ W[64,DOUT]
// 64-row x DOUT-col tile per 256-thread block, 4x4 outputs per thread.
// RELU_IN applies relu to X on load (fuses previous layer's activation).
// ---------------------------------------------------------------------------
template<int DOUT, bool RELU_IN>
__global__ __launch_bounds__(256) void gemm_tile(const float* __restrict__ X,
                                                 const float* __restrict__ W,
                                                 float* __restrict__ H) {
    __shared__ float Xs[64][68];          // +4 pad: 16B-aligned rows, banks spread
    __shared__ float Ws[64 * DOUT];
    const int tid = threadIdx.x;

    // load W tile (64*DOUT floats) as float4
    for (int i = tid; i < 64 * DOUT / 4; i += 256) {
        reinterpret_cast<float4*>(Ws)[i] = reinterpret_cast<const float4*>(W)[i];
    }

    const int row0 = blockIdx.x * 64;
    // load X tile (64x64 floats) coalesced, 4 float4 per thread
#pragma unroll
    for (int p = 0; p < 4; ++p) {
        int idx = p * 256 + tid;          // float4 index 0..1023
        int r = idx >> 4;                 // 0..63
        int c = (idx & 15) << 2;          // 0,4,..,60
        float4 v = make_float4(0.f, 0.f, 0.f, 0.f);
        if (row0 + r < N_NODES) {
            v = *reinterpret_cast<const float4*>(X + (size_t)(row0 + r) * 64 + c);
        }
        if (RELU_IN) {
            v.x = fmaxf(v.x, 0.f); v.y = fmaxf(v.y, 0.f);
            v.z = fmaxf(v.z, 0.f); v.w = fmaxf(v.w, 0.f);
        }
        *reinterpret_cast<float4*>(&Xs[r][c]) = v;
    }
    __syncthreads();

    const int tr = (tid >> 4) << 2;       // row offset within tile: 0,4,..,60
    const int tc = (tid & 15) << 2;       // col offset: 0,4,..,60
    if (tc < DOUT) {
        float acc[4][4];
#pragma unroll
        for (int i = 0; i < 4; ++i)
#pragma unroll
            for (int j = 0; j < 4; ++j) acc[i][j] = 0.f;

#pragma unroll 8
        for (int k = 0; k < 64; ++k) {
            float4 wv = *reinterpret_cast<const float4*>(&Ws[k * DOUT + tc]);
            float xv[4];
#pragma unroll
            for (int i = 0; i < 4; ++i) xv[i] = Xs[tr + i][k];
#pragma unroll
            for (int i = 0; i < 4; ++i) {
                acc[i][0] += xv[i] * wv.x;
                acc[i][1] += xv[i] * wv.y;
                acc[i][2] += xv[i] * wv.z;
                acc[i][3] += xv[i] * wv.w;
            }
        }
#pragma unroll
        for (int i = 0; i < 4; ++i) {
            int r = row0 + tr + i;
            if (r < N_NODES) {
                *reinterpret_cast<float4*>(H + (size_t)r * DOUT + tc) =
                    make_float4(acc[i][0], acc[i][1], acc[i][2], acc[i][3]);
            }
        }
    }
}

// ---------------------------------------------------------------------------
// Initialize aggregation buffer to broadcast bias: A[n*DOUT + c] = b[c]
// ---------------------------------------------------------------------------
template<int DOUT>
__global__ __launch_bounds__(256) void init_bias(float* __restrict__ A,
                                                 const float* __restrict__ b) {
    int i = blockIdx.x * 256 + threadIdx.x;
    if (i < N_NODES * DOUT) {
        A[i] = b[i % DOUT];
    }
}

// ---------------------------------------------------------------------------
// Scatter-add: AGG[dst[e]] += H[src[e]] * w[e], one wave per edge,
// lane = channel. Edge metadata goes through SGPR (wave-uniform index).
// ---------------------------------------------------------------------------
template<int DOUT>
__global__ __launch_bounds__(256) void scatter_add(const float* __restrict__ H,
                                                   const int* __restrict__ src,
                                                   const int* __restrict__ dst,
                                                   const float* __restrict__ ew,
                                                   float* __restrict__ AGG) {
    const int lane = threadIdx.x & 63;
    const int wave = __builtin_amdgcn_readfirstlane(
        (int)((blockIdx.x * blockDim.x + threadIdx.x) >> 6));
    const int nwaves = (int)((gridDim.x * blockDim.x) >> 6);
    for (int e = wave; e < E_EDGES; e += nwaves) {
        const int s = src[e];
        const int d = dst[e];
        const float wt = ew[e];
        if (DOUT == 64 || lane < DOUT) {
            const float v = H[(size_t)s * DOUT + lane] * wt;
            atomicAdd(&AGG[(size_t)d * DOUT + lane], v);
        }
    }
}

// ---------------------------------------------------------------------------
// Launch: 5 layers. Layer i: gemm(in -> H), init(AGG=b), scatter(H -> AGG).
// ReLU of layer i fused into layer i+1's gemm input load.
// ---------------------------------------------------------------------------
extern "C" void kernel_launch(void* const* d_in, const int* in_sizes, int n_in,
                              void* d_out, int out_size, void* d_ws, size_t ws_size,
                              hipStream_t stream) {
    const float* x    = (const float*)d_in[0];
    const float* ew   = (const float*)d_in[1];
    const float* W    = (const float*)d_in[2];   // [4,64,64]
    const float* b    = (const float*)d_in[3];   // [4,64]
    const float* Wout = (const float*)d_in[4];   // [64,40]
    const float* bout = (const float*)d_in[5];   // [40]
    const int*   src  = (const int*)d_in[6];
    const int*   dst  = (const int*)d_in[7];
    float* out = (float*)d_out;

    float* H   = (float*)d_ws;                       // N*64 floats
    float* AGG = H + (size_t)N_NODES * 64;           // N*64 floats

    dim3 blk(256);
    const int gemmGrid   = (N_NODES + 63) / 64;             // 1563
    const int initGrid64 = (N_NODES * 64 + 255) / 256;
    const int initGrid40 = (N_NODES * 40 + 255) / 256;
    const int scatGrid   = 4096;                            // grid-stride waves

    // layer 0: input x, no relu on load
    gemm_tile<64, false><<<gemmGrid, blk, 0, stream>>>(x, W, H);
    init_bias<64><<<initGrid64, blk, 0, stream>>>(AGG, b);
    scatter_add<64><<<scatGrid, blk, 0, stream>>>(H, src, dst, ew, AGG);

    // layers 1..3: relu(prev) @ W[i]
    for (int i = 1; i < 4; ++i) {
        gemm_tile<64, true><<<gemmGrid, blk, 0, stream>>>(AGG, W + (size_t)i * 64 * 64, H);
        init_bias<64><<<initGrid64, blk, 0, stream>>>(AGG, b + (size_t)i * 64);
        scatter_add<64><<<scatGrid, blk, 0, stream>>>(H, src, dst, ew, AGG);
    }

    // final layer: relu(prev) @ W_out -> [N,40], scatter straight into d_out
    gemm_tile<40, true><<<gemmGrid, blk, 0, stream>>>(AGG, Wout, H);
    init_bias<40><<<initGrid40, blk, 0, stream>>>(out, bout);
    scatter_add<40><<<scatGrid, blk, 0, stream>>>(H, src, dst, ew, out);
}

// Round 2
// 635.047 us; speedup vs baseline: 2.7305x; 2.7305x over previous
//
#include <hip/hip_runtime.h>

#define N_NODES 100000
#define E_EDGES 1600000
#define SCAN_CHUNK 1024
#define SCAN_NB ((N_NODES + SCAN_CHUNK - 1) / SCAN_CHUNK)   // 98

// ---------------------------------------------------------------------------
// GEMM: H[N,DOUT] = act(X)[N,64] @ W[64,DOUT]
// ---------------------------------------------------------------------------
template<int DOUT, bool RELU_IN>
__global__ __launch_bounds__(256) void gemm_tile(const float* __restrict__ X,
                                                 const float* __restrict__ W,
                                                 float* __restrict__ H) {
    __shared__ float Xs[64][68];
    __shared__ float Ws[64 * DOUT];
    const int tid = threadIdx.x;

    for (int i = tid; i < 64 * DOUT / 4; i += 256) {
        reinterpret_cast<float4*>(Ws)[i] = reinterpret_cast<const float4*>(W)[i];
    }

    const int row0 = blockIdx.x * 64;
#pragma unroll
    for (int p = 0; p < 4; ++p) {
        int idx = p * 256 + tid;
        int r = idx >> 4;
        int c = (idx & 15) << 2;
        float4 v = make_float4(0.f, 0.f, 0.f, 0.f);
        if (row0 + r < N_NODES) {
            v = *reinterpret_cast<const float4*>(X + (size_t)(row0 + r) * 64 + c);
        }
        if (RELU_IN) {
            v.x = fmaxf(v.x, 0.f); v.y = fmaxf(v.y, 0.f);
            v.z = fmaxf(v.z, 0.f); v.w = fmaxf(v.w, 0.f);
        }
        *reinterpret_cast<float4*>(&Xs[r][c]) = v;
    }
    __syncthreads();

    const int tr = (tid >> 4) << 2;
    const int tc = (tid & 15) << 2;
    if (tc < DOUT) {
        float acc[4][4];
#pragma unroll
        for (int i = 0; i < 4; ++i)
#pragma unroll
            for (int j = 0; j < 4; ++j) acc[i][j] = 0.f;

#pragma unroll 8
        for (int k = 0; k < 64; ++k) {
            float4 wv = *reinterpret_cast<const float4*>(&Ws[k * DOUT + tc]);
            float xv[4];
#pragma unroll
            for (int i = 0; i < 4; ++i) xv[i] = Xs[tr + i][k];
#pragma unroll
            for (int i = 0; i < 4; ++i) {
                acc[i][0] += xv[i] * wv.x;
                acc[i][1] += xv[i] * wv.y;
                acc[i][2] += xv[i] * wv.z;
                acc[i][3] += xv[i] * wv.w;
            }
        }
#pragma unroll
        for (int i = 0; i < 4; ++i) {
            int r = row0 + tr + i;
            if (r < N_NODES) {
                *reinterpret_cast<float4*>(H + (size_t)r * DOUT + tc) =
                    make_float4(acc[i][0], acc[i][1], acc[i][2], acc[i][3]);
            }
        }
    }
}

// ---------------------------------------------------------------------------
// CSR build: histogram -> exclusive scan -> permute
// ---------------------------------------------------------------------------
__global__ __launch_bounds__(256) void hist_kernel(const int* __restrict__ dst,
                                                   int* __restrict__ deg) {
    int e = blockIdx.x * 256 + threadIdx.x;
    if (e < E_EDGES) atomicAdd(&deg[dst[e]], 1);
}

// per-chunk exclusive scan (chunk = 1024 elems, 256 thr x 4 elems)
__global__ __launch_bounds__(256) void scan_blocks(const int* __restrict__ deg,
                                                   int* __restrict__ off,
                                                   int* __restrict__ blockSums) {
    __shared__ int wsum[4];
    const int tid = threadIdx.x, lane = tid & 63, wv = tid >> 6;
    const int base = blockIdx.x * SCAN_CHUNK + tid * 4;
    int v[4];
    int s = 0;
#pragma unroll
    for (int j = 0; j < 4; ++j) {
        v[j] = (base + j < N_NODES) ? deg[base + j] : 0;
        s += v[j];
    }
    int inc = s;
#pragma unroll
    for (int o = 1; o < 64; o <<= 1) {
        int t = __shfl_up(inc, o, 64);
        if (lane >= o) inc += t;
    }
    if (lane == 63) wsum[wv] = inc;
    __syncthreads();
    int woff = 0;
    for (int w2 = 0; w2 < wv; ++w2) woff += wsum[w2];
    int run = woff + inc - s;   // exclusive offset for this thread's 4 elems
#pragma unroll
    for (int j = 0; j < 4; ++j) {
        if (base + j < N_NODES) off[base + j] = run;
        run += v[j];
    }
    if (tid == 255) blockSums[blockIdx.x] = woff + inc;
}

// scan the 98 block sums (1 block, 128 threads = 2 waves)
__global__ __launch_bounds__(128) void scan_mid(const int* __restrict__ blockSums,
                                                int* __restrict__ blockOff,
                                                int* __restrict__ off) {
    __shared__ int wsum[2];
    const int tid = threadIdx.x, lane = tid & 63, wv = tid >> 6;
    int v = (tid < SCAN_NB) ? blockSums[tid] : 0;
    int inc = v;
#pragma unroll
    for (int o = 1; o < 64; o <<= 1) {
        int t = __shfl_up(inc, o, 64);
        if (lane >= o) inc += t;
    }
    if (lane == 63) wsum[wv] = inc;
    __syncthreads();
    int woff = (wv == 1) ? wsum[0] : 0;
    if (tid < SCAN_NB) blockOff[tid] = woff + inc - v;
    if (tid == SCAN_NB - 1) off[N_NODES] = woff + inc;   // total == E
}

__global__ __launch_bounds__(256) void scan_add(int* __restrict__ off,
                                                const int* __restrict__ blockOff) {
    const int base = blockIdx.x * SCAN_CHUNK + threadIdx.x * 4;
    const int a = blockOff[blockIdx.x];
#pragma unroll
    for (int j = 0; j < 4; ++j) {
        if (base + j < N_NODES) off[base + j] += a;
    }
}

__global__ __launch_bounds__(256) void fill_csr(const int* __restrict__ src,
                                                const int* __restrict__ dst,
                                                const float* __restrict__ ew,
                                                int* __restrict__ cursor,
                                                int* __restrict__ csr_src,
                                                float* __restrict__ csr_w) {
    int e = blockIdx.x * 256 + threadIdx.x;
    if (e < E_EDGES) {
        int d = dst[e];
        int p = atomicAdd(&cursor[d], 1);
        csr_src[p] = src[e];
        csr_w[p]   = ew[e];
    }
}

// ---------------------------------------------------------------------------
// Aggregate: one wave per dst node, lane = channel.
// AGG[n] = b + sum_k w_k * H[src_k]   (no atomics)
// ---------------------------------------------------------------------------
template<int DOUT>
__global__ __launch_bounds__(256) void aggregate(const float* __restrict__ H,
                                                 const int* __restrict__ off,
                                                 const int* __restrict__ csr_src,
                                                 const float* __restrict__ csr_w,
                                                 const float* __restrict__ bvec,
                                                 float* __restrict__ AGG) {
    const int node = (int)((blockIdx.x * 256 + threadIdx.x) >> 6);
    const int lane = threadIdx.x & 63;
    if (node >= N_NODES) return;
    const int k0 = __builtin_amdgcn_readfirstlane(off[node]);
    const int k1 = __builtin_amdgcn_readfirstlane(off[node + 1]);
    const bool active = (DOUT == 64) || (lane < DOUT);
    float acc = active ? bvec[lane] : 0.f;
    int k = k0;
    for (; k + 1 < k1; k += 2) {
        int   s0 = csr_src[k],     s1 = csr_src[k + 1];
        float w0 = csr_w[k],       w1 = csr_w[k + 1];
        float h0 = 0.f, h1 = 0.f;
        if (active) {
            h0 = H[(size_t)s0 * DOUT + lane];
            h1 = H[(size_t)s1 * DOUT + lane];
        }
        acc += h0 * w0 + h1 * w1;
    }
    if (k < k1) {
        int   s0 = csr_src[k];
        float w0 = csr_w[k];
        if (active) acc += H[(size_t)s0 * DOUT + lane] * w0;
    }
    if (active) AGG[(size_t)node * DOUT + lane] = acc;
}

// ---------------------------------------------------------------------------
extern "C" void kernel_launch(void* const* d_in, const int* in_sizes, int n_in,
                              void* d_out, int out_size, void* d_ws, size_t ws_size,
                              hipStream_t stream) {
    const float* x    = (const float*)d_in[0];
    const float* ew   = (const float*)d_in[1];
    const float* W    = (const float*)d_in[2];   // [4,64,64]
    const float* b    = (const float*)d_in[3];   // [4,64]
    const float* Wout = (const float*)d_in[4];   // [64,40]
    const float* bout = (const float*)d_in[5];   // [40]
    const int*   src  = (const int*)d_in[6];
    const int*   dst  = (const int*)d_in[7];
    float* out = (float*)d_out;

    // workspace layout
    float* H       = (float*)d_ws;                          // N*64 f
    float* AGG     = H + (size_t)N_NODES * 64;              // N*64 f
    int*   deg     = (int*)(AGG + (size_t)N_NODES * 64);    // N
    int*   off     = deg + N_NODES;                         // N+1
    int*   cursor  = off + N_NODES + 1;                     // N
    int*   bsums   = cursor + N_NODES;                      // SCAN_NB
    int*   boff    = bsums + SCAN_NB;                       // SCAN_NB
    int*   csr_src = boff + SCAN_NB;                        // E
    float* csr_w   = (float*)(csr_src + E_EDGES);           // E

    dim3 blk(256);
    const int gemmGrid  = (N_NODES + 63) / 64;              // 1563
    const int edgeGrid  = (E_EDGES + 255) / 256;            // 6250
    const int aggGrid   = (N_NODES * 64 + 255) / 256;       // 25000

    // ---- build CSR (once; reused by all 5 layers) ----
    hipMemsetAsync(deg, 0, N_NODES * sizeof(int), stream);
    hist_kernel<<<edgeGrid, blk, 0, stream>>>(dst, deg);
    scan_blocks<<<SCAN_NB, blk, 0, stream>>>(deg, off, bsums);
    scan_mid<<<1, 128, 0, stream>>>(bsums, boff, off);
    scan_add<<<SCAN_NB, blk, 0, stream>>>(off, boff);
    hipMemcpyAsync(cursor, off, N_NODES * sizeof(int), hipMemcpyDeviceToDevice, stream);
    fill_csr<<<edgeGrid, blk, 0, stream>>>(src, dst, ew, cursor, csr_src, csr_w);

    // ---- layer 0 ----
    gemm_tile<64, false><<<gemmGrid, blk, 0, stream>>>(x, W, H);
    aggregate<64><<<aggGrid, blk, 0, stream>>>(H, off, csr_src, csr_w, b, AGG);

    // ---- layers 1..3 ----
    for (int i = 1; i < 4; ++i) {
        gemm_tile<64, true><<<gemmGrid, blk, 0, stream>>>(AGG, W + (size_t)i * 64 * 64, H);
        aggregate<64><<<aggGrid, blk, 0, stream>>>(H, off, csr_src, csr_w, b + (size_t)i * 64, AGG);
    }

    // ---- final layer -> d_out [N,40] ----
    gemm_tile<40, true><<<gemmGrid, blk, 0, stream>>>(AGG, Wout, H);
    aggregate<40><<<aggGrid, blk, 0, stream>>>(H, off, csr_src, csr_w, bout, out);
}

// Round 3
// 579.216 us; speedup vs baseline: 2.9937x; 1.0964x over previous
//
#include <hip/hip_runtime.h>

#define N_NODES 100000
#define E_EDGES 1600000
#define SCAN_CHUNK 1024
#define SCAN_NB ((N_NODES + SCAN_CHUNK - 1) / SCAN_CHUNK)   // 98

// ---------------------------------------------------------------------------
// GEMM: H[N,DOUT] = act(X)[N,64] @ W[64,DOUT]
// ---------------------------------------------------------------------------
template<int DOUT, bool RELU_IN>
__global__ __launch_bounds__(256) void gemm_tile(const float* __restrict__ X,
                                                 const float* __restrict__ W,
                                                 float* __restrict__ H) {
    __shared__ float Xs[64][68];
    __shared__ float Ws[64 * DOUT];
    const int tid = threadIdx.x;

    for (int i = tid; i < 64 * DOUT / 4; i += 256) {
        reinterpret_cast<float4*>(Ws)[i] = reinterpret_cast<const float4*>(W)[i];
    }

    const int row0 = blockIdx.x * 64;
#pragma unroll
    for (int p = 0; p < 4; ++p) {
        int idx = p * 256 + tid;
        int r = idx >> 4;
        int c = (idx & 15) << 2;
        float4 v = make_float4(0.f, 0.f, 0.f, 0.f);
        if (row0 + r < N_NODES) {
            v = *reinterpret_cast<const float4*>(X + (size_t)(row0 + r) * 64 + c);
        }
        if (RELU_IN) {
            v.x = fmaxf(v.x, 0.f); v.y = fmaxf(v.y, 0.f);
            v.z = fmaxf(v.z, 0.f); v.w = fmaxf(v.w, 0.f);
        }
        *reinterpret_cast<float4*>(&Xs[r][c]) = v;
    }
    __syncthreads();

    const int tr = (tid >> 4) << 2;
    const int tc = (tid & 15) << 2;
    if (tc < DOUT) {
        float acc[4][4];
#pragma unroll
        for (int i = 0; i < 4; ++i)
#pragma unroll
            for (int j = 0; j < 4; ++j) acc[i][j] = 0.f;

#pragma unroll 8
        for (int k = 0; k < 64; ++k) {
            float4 wv = *reinterpret_cast<const float4*>(&Ws[k * DOUT + tc]);
            float xv[4];
#pragma unroll
            for (int i = 0; i < 4; ++i) xv[i] = Xs[tr + i][k];
#pragma unroll
            for (int i = 0; i < 4; ++i) {
                acc[i][0] += xv[i] * wv.x;
                acc[i][1] += xv[i] * wv.y;
                acc[i][2] += xv[i] * wv.z;
                acc[i][3] += xv[i] * wv.w;
            }
        }
#pragma unroll
        for (int i = 0; i < 4; ++i) {
            int r = row0 + tr + i;
            if (r < N_NODES) {
                *reinterpret_cast<float4*>(H + (size_t)r * DOUT + tc) =
                    make_float4(acc[i][0], acc[i][1], acc[i][2], acc[i][3]);
            }
        }
    }
}

// ---------------------------------------------------------------------------
// CSR build: histogram -> exclusive scan -> permute (packed 8B entries)
// ---------------------------------------------------------------------------
__global__ __launch_bounds__(256) void hist_kernel(const int* __restrict__ dst,
                                                   int* __restrict__ deg) {
    int e = blockIdx.x * 256 + threadIdx.x;
    if (e < E_EDGES) atomicAdd(&deg[dst[e]], 1);
}

__global__ __launch_bounds__(256) void scan_blocks(const int* __restrict__ deg,
                                                   int* __restrict__ off,
                                                   int* __restrict__ blockSums) {
    __shared__ int wsum[4];
    const int tid = threadIdx.x, lane = tid & 63, wv = tid >> 6;
    const int base = blockIdx.x * SCAN_CHUNK + tid * 4;
    int v[4];
    int s = 0;
#pragma unroll
    for (int j = 0; j < 4; ++j) {
        v[j] = (base + j < N_NODES) ? deg[base + j] : 0;
        s += v[j];
    }
    int inc = s;
#pragma unroll
    for (int o = 1; o < 64; o <<= 1) {
        int t = __shfl_up(inc, o, 64);
        if (lane >= o) inc += t;
    }
    if (lane == 63) wsum[wv] = inc;
    __syncthreads();
    int woff = 0;
    for (int w2 = 0; w2 < wv; ++w2) woff += wsum[w2];
    int run = woff + inc - s;
#pragma unroll
    for (int j = 0; j < 4; ++j) {
        if (base + j < N_NODES) off[base + j] = run;
        run += v[j];
    }
    if (tid == 255) blockSums[blockIdx.x] = woff + inc;
}

__global__ __launch_bounds__(128) void scan_mid(const int* __restrict__ blockSums,
                                                int* __restrict__ blockOff,
                                                int* __restrict__ off) {
    __shared__ int wsum[2];
    const int tid = threadIdx.x, lane = tid & 63, wv = tid >> 6;
    int v = (tid < SCAN_NB) ? blockSums[tid] : 0;
    int inc = v;
#pragma unroll
    for (int o = 1; o < 64; o <<= 1) {
        int t = __shfl_up(inc, o, 64);
        if (lane >= o) inc += t;
    }
    if (lane == 63) wsum[wv] = inc;
    __syncthreads();
    int woff = (wv == 1) ? wsum[0] : 0;
    if (tid < SCAN_NB) blockOff[tid] = woff + inc - v;
    if (tid == SCAN_NB - 1) off[N_NODES] = woff + inc;
}

__global__ __launch_bounds__(256) void scan_add(int* __restrict__ off,
                                                const int* __restrict__ blockOff) {
    const int base = blockIdx.x * SCAN_CHUNK + threadIdx.x * 4;
    const int a = blockOff[blockIdx.x];
#pragma unroll
    for (int j = 0; j < 4; ++j) {
        if (base + j < N_NODES) off[base + j] += a;
    }
}

__global__ __launch_bounds__(256) void fill_csr(const int* __restrict__ src,
                                                const int* __restrict__ dst,
                                                const float* __restrict__ ew,
                                                int* __restrict__ cursor,
                                                int2* __restrict__ csr) {
    int e = blockIdx.x * 256 + threadIdx.x;
    if (e < E_EDGES) {
        int d = dst[e];
        int p = atomicAdd(&cursor[d], 1);
        csr[p] = make_int2(src[e], __float_as_int(ew[e]));   // one 8B store
    }
}

// ---------------------------------------------------------------------------
// Aggregate: one wave per dst node, lane = channel, unroll-4 gathers.
// AGG[n] = b + sum_k w_k * H[src_k]   (no atomics)
// ---------------------------------------------------------------------------
template<int DOUT>
__global__ __launch_bounds__(256) void aggregate(const float* __restrict__ H,
                                                 const int* __restrict__ off,
                                                 const int2* __restrict__ csr,
                                                 const float* __restrict__ bvec,
                                                 float* __restrict__ AGG) {
    const int node = (int)((blockIdx.x * 256 + threadIdx.x) >> 6);
    const int lane = threadIdx.x & 63;
    if (node >= N_NODES) return;
    const int k0 = __builtin_amdgcn_readfirstlane(off[node]);
    const int k1 = __builtin_amdgcn_readfirstlane(off[node + 1]);
    const bool active = (DOUT == 64) || (lane < DOUT);
    float acc = active ? bvec[lane] : 0.f;
    int k = k0;
    for (; k + 3 < k1; k += 4) {
        int2 e0 = csr[k], e1 = csr[k + 1], e2 = csr[k + 2], e3 = csr[k + 3];
        int s0 = __builtin_amdgcn_readfirstlane(e0.x);
        int s1 = __builtin_amdgcn_readfirstlane(e1.x);
        int s2 = __builtin_amdgcn_readfirstlane(e2.x);
        int s3 = __builtin_amdgcn_readfirstlane(e3.x);
        float h0 = 0.f, h1 = 0.f, h2 = 0.f, h3 = 0.f;
        if (active) {
            h0 = H[(size_t)s0 * DOUT + lane];
            h1 = H[(size_t)s1 * DOUT + lane];
            h2 = H[(size_t)s2 * DOUT + lane];
            h3 = H[(size_t)s3 * DOUT + lane];
        }
        acc += h0 * __int_as_float(e0.y) + h1 * __int_as_float(e1.y)
             + h2 * __int_as_float(e2.y) + h3 * __int_as_float(e3.y);
    }
    for (; k < k1; ++k) {
        int2 e0 = csr[k];
        int s0 = __builtin_amdgcn_readfirstlane(e0.x);
        if (active) acc += H[(size_t)s0 * DOUT + lane] * __int_as_float(e0.y);
    }
    if (active) AGG[(size_t)node * DOUT + lane] = acc;
}

// ---------------------------------------------------------------------------
extern "C" void kernel_launch(void* const* d_in, const int* in_sizes, int n_in,
                              void* d_out, int out_size, void* d_ws, size_t ws_size,
                              hipStream_t stream) {
    const float* x    = (const float*)d_in[0];
    const float* ew   = (const float*)d_in[1];
    const float* W    = (const float*)d_in[2];   // [4,64,64]
    const float* b    = (const float*)d_in[3];   // [4,64]
    const float* Wout = (const float*)d_in[4];   // [64,40]
    const float* bout = (const float*)d_in[5];   // [40]
    const int*   src  = (const int*)d_in[6];
    const int*   dst  = (const int*)d_in[7];
    float* out = (float*)d_out;

    // workspace layout
    float* H       = (float*)d_ws;                          // N*64 f
    float* AGG     = H + (size_t)N_NODES * 64;              // N*64 f
    int*   deg     = (int*)(AGG + (size_t)N_NODES * 64);    // N
    int*   off     = deg + N_NODES;                         // N+1
    int*   cursor  = off + N_NODES + 1;                     // N
    int*   bsums   = cursor + N_NODES;                      // SCAN_NB
    int*   boff    = bsums + SCAN_NB;                       // SCAN_NB
    int*   pad     = boff + SCAN_NB;
    int2*  csr     = (int2*)(((uintptr_t)pad + 15) & ~(uintptr_t)15);  // E packed

    dim3 blk(256);
    const int gemmGrid  = (N_NODES + 63) / 64;              // 1563
    const int edgeGrid  = (E_EDGES + 255) / 256;            // 6250
    const int aggGrid   = (N_NODES * 64 + 255) / 256;       // 25000

    // ---- build CSR (once; reused by all 5 layers) ----
    hipMemsetAsync(deg, 0, N_NODES * sizeof(int), stream);
    hist_kernel<<<edgeGrid, blk, 0, stream>>>(dst, deg);
    scan_blocks<<<SCAN_NB, blk, 0, stream>>>(deg, off, bsums);
    scan_mid<<<1, 128, 0, stream>>>(bsums, boff, off);
    scan_add<<<SCAN_NB, blk, 0, stream>>>(off, boff);
    hipMemcpyAsync(cursor, off, N_NODES * sizeof(int), hipMemcpyDeviceToDevice, stream);
    fill_csr<<<edgeGrid, blk, 0, stream>>>(src, dst, ew, cursor, csr);

    // ---- layer 0 ----
    gemm_tile<64, false><<<gemmGrid, blk, 0, stream>>>(x, W, H);
    aggregate<64><<<aggGrid, blk, 0, stream>>>(H, off, csr, b, AGG);

    // ---- layers 1..3 ----
    for (int i = 1; i < 4; ++i) {
        gemm_tile<64, true><<<gemmGrid, blk, 0, stream>>>(AGG, W + (size_t)i * 64 * 64, H);
        aggregate<64><<<aggGrid, blk, 0, stream>>>(H, off, csr, b + (size_t)i * 64, AGG);
    }

    // ---- final layer -> d_out [N,40] ----
    gemm_tile<40, true><<<gemmGrid, blk, 0, stream>>>(AGG, Wout, H);
    aggregate<40><<<aggGrid, blk, 0, stream>>>(H, off, csr, bout, out);
}